// Round 1
// baseline (357.689 us; speedup 1.0000x reference)
//
#include <hip/hip_runtime.h>
#include <hip/hip_bf16.h>
#include <stdint.h>

#define N_ROWS 16384
#define M_ROWS 4096
#define DDIM   512

using frag_ab = __attribute__((ext_vector_type(8))) short;  // 8 bf16 (4 VGPRs)
using frag_cd = __attribute__((ext_vector_type(4))) float;  // 4 fp32 acc

__device__ __forceinline__ unsigned short f2bf(float f) {
  unsigned int u = __float_as_uint(f);
  u += 0x7fffu + ((u >> 16) & 1u);   // round-to-nearest-even
  return (unsigned short)(u >> 16);
}

// One wave per row: fp32 -> bf16 conversion + fp32 row-norm.
// Rows [0, N) are `input`, rows [N, N+M) are `centres`.
__global__ void rbf_convert_kernel(const float* __restrict__ in,
                                   const float* __restrict__ cen,
                                   unsigned short* __restrict__ a_bf,
                                   unsigned short* __restrict__ b_bf,
                                   float* __restrict__ x_sq,
                                   float* __restrict__ c_sq) {
  const int wave = threadIdx.x >> 6;
  const int lane = threadIdx.x & 63;
  const int row  = blockIdx.x * 4 + wave;

  const float* src;
  unsigned short* dst;
  float* nrm;
  if (row < N_ROWS) {
    src = in + (long)row * DDIM;
    dst = a_bf + (long)row * DDIM;
    nrm = x_sq + row;
  } else {
    const int rr = row - N_ROWS;
    src = cen + (long)rr * DDIM;
    dst = b_bf + (long)rr * DDIM;
    nrm = c_sq + rr;
  }

  float sum = 0.f;
#pragma unroll
  for (int it = 0; it < 2; ++it) {
    const int col = it * 256 + lane * 4;
    float4 v = *(const float4*)(src + col);
    sum += v.x * v.x + v.y * v.y + v.z * v.z + v.w * v.w;
    ushort4 p;
    p.x = f2bf(v.x); p.y = f2bf(v.y); p.z = f2bf(v.z); p.w = f2bf(v.w);
    *(ushort4*)(dst + col) = p;
  }
#pragma unroll
  for (int off = 32; off > 0; off >>= 1) sum += __shfl_down(sum, off, 64);
  if (lane == 0) *nrm = sum;
}

// 128x128 tile GEMM-with-epilogue: out = x_sq + c_sq - 2 * (A . B^T)
// m97 structure: global_load_lds width=16 staging, 16x16x32 bf16 MFMA,
// 4 waves each computing a 64x64 subtile (4x4 MFMA tiles).
__global__ __launch_bounds__(256) void rbf_gemm_kernel(
    const unsigned short* __restrict__ a_bf,
    const unsigned short* __restrict__ b_bf,
    const float* __restrict__ x_sq,
    const float* __restrict__ c_sq,
    float* __restrict__ out) {
  // Unpadded, lane-contiguous layout (required by global_load_lds:
  // dest = wave-uniform base + lane*16B). [row][k] rows of 32 bf16.
  __shared__ __attribute__((aligned(16))) unsigned short A_lds[128 * 32];
  __shared__ __attribute__((aligned(16))) unsigned short B_lds[128 * 32];

  const int tid    = threadIdx.x;
  const int wave   = tid >> 6;
  const int lane   = tid & 63;
  const int lane15 = lane & 15;
  const int quad   = lane >> 4;
  const int wr     = wave >> 1;  // wave row (0..1) -> 64-row half
  const int wc     = wave & 1;   // wave col (0..1) -> 64-col half
  const int n0     = blockIdx.y * 128;
  const int m0     = blockIdx.x * 128;

  frag_cd acc[4][4];
#pragma unroll
  for (int i = 0; i < 4; ++i)
#pragma unroll
    for (int j = 0; j < 4; ++j)
      acc[i][j] = (frag_cd){0.f, 0.f, 0.f, 0.f};

  for (int kb = 0; kb < DDIM / 32; ++kb) {
    const int k0 = kb * 32;
    // Stage A and B tiles: 512 chunks of 16B each; chunk c -> row=c>>2, kc=c&3.
#pragma unroll
    for (int it = 0; it < 2; ++it) {
      const int cbase = (it * 4 + wave) * 64;  // wave-uniform
      const int c     = cbase + lane;
      const int row   = c >> 2;
      const int kc    = c & 3;
      const unsigned short* ga = a_bf + (long)(n0 + row) * DDIM + k0 + kc * 8;
      const unsigned short* gb = b_bf + (long)(m0 + row) * DDIM + k0 + kc * 8;
      __builtin_amdgcn_global_load_lds(
          (const __attribute__((address_space(1))) unsigned int*)ga,
          (__attribute__((address_space(3))) unsigned int*)&A_lds[cbase * 8],
          16, 0, 0);
      __builtin_amdgcn_global_load_lds(
          (const __attribute__((address_space(1))) unsigned int*)gb,
          (__attribute__((address_space(3))) unsigned int*)&B_lds[cbase * 8],
          16, 0, 0);
    }
    __syncthreads();  // compiler emits vmcnt(0) drain before barrier

    frag_ab a_frag[4], b_frag[4];
#pragma unroll
    for (int i = 0; i < 4; ++i) {
      const int r = wr * 64 + i * 16 + lane15;
      a_frag[i] = *(const frag_ab*)&A_lds[r * 32 + quad * 8];
    }
#pragma unroll
    for (int j = 0; j < 4; ++j) {
      const int r = wc * 64 + j * 16 + lane15;
      b_frag[j] = *(const frag_ab*)&B_lds[r * 32 + quad * 8];
    }
#pragma unroll
    for (int i = 0; i < 4; ++i)
#pragma unroll
      for (int j = 0; j < 4; ++j)
        acc[i][j] = __builtin_amdgcn_mfma_f32_16x16x32_bf16(
            a_frag[i], b_frag[j], acc[i][j], 0, 0, 0);
    __syncthreads();
  }

  // Epilogue: out[r][c] = x_sq[r] + c_sq[c] - 2*dot.
  // C/D layout: col = lane&15, row = quad*4 + reg (m89-verified).
  float cs[4];
#pragma unroll
  for (int j = 0; j < 4; ++j) cs[j] = c_sq[m0 + wc * 64 + j * 16 + lane15];

#pragma unroll
  for (int i = 0; i < 4; ++i) {
#pragma unroll
    for (int reg = 0; reg < 4; ++reg) {
      const int r = n0 + wr * 64 + i * 16 + quad * 4 + reg;
      const float xv = x_sq[r];
      float* orow = out + (long)r * M_ROWS + m0 + wc * 64 + lane15;
#pragma unroll
      for (int j = 0; j < 4; ++j) {
        orow[j * 16] = xv + cs[j] - 2.0f * acc[i][j][reg];
      }
    }
  }
}

extern "C" void kernel_launch(void* const* d_in, const int* in_sizes, int n_in,
                              void* d_out, int out_size, void* d_ws, size_t ws_size,
                              hipStream_t stream) {
  const float* input   = (const float*)d_in[0];
  const float* centres = (const float*)d_in[1];
  float* out = (float*)d_out;

  // Workspace layout (~20.1 MB):
  //   a_bf: N*D bf16 (16 MiB) | b_bf: M*D bf16 (4 MiB) | x_sq: N f32 | c_sq: M f32
  char* ws = (char*)d_ws;
  unsigned short* a_bf = (unsigned short*)ws;
  unsigned short* b_bf = (unsigned short*)(ws + (size_t)N_ROWS * DDIM * 2);
  float* x_sq = (float*)(ws + (size_t)N_ROWS * DDIM * 2 + (size_t)M_ROWS * DDIM * 2);
  float* c_sq = x_sq + N_ROWS;

  rbf_convert_kernel<<<(N_ROWS + M_ROWS) / 4, 256, 0, stream>>>(
      input, centres, a_bf, b_bf, x_sq, c_sq);

  dim3 grid(M_ROWS / 128, N_ROWS / 128);
  rbf_gemm_kernel<<<grid, 256, 0, stream>>>(a_bf, b_bf, x_sq, c_sq, out);
}